// Round 11
// baseline (248.642 us; speedup 1.0000x reference)
//
#include <hip/hip_runtime.h>
#include <math.h>

#define BATCH 128
#define ACT 7
#define NC 100
#define CTXD 128
#define HID 512
#define QW 600               // q cols 600..699 of reference are exactly 0

typedef __attribute__((ext_vector_type(8))) __bf16 bf16x8;
typedef __attribute__((ext_vector_type(4))) float f32x4;
typedef __attribute__((ext_vector_type(4))) unsigned short u16x4;

__device__ __forceinline__ unsigned short f2bf(float f) {
    union { float f; unsigned int u; } v; v.f = f;
    unsigned int u = v.u;
    return (unsigned short)((u + 0x7fffu + ((u >> 16) & 1u)) >> 16);
}
__device__ __forceinline__ unsigned int pack2bf(float a, float b) {
    unsigned int ua = __float_as_uint(a) + 0x8000u;
    unsigned int ub = __float_as_uint(b) + 0x8000u;
    return (ua >> 16) | (ub & 0xffff0000u);
}

__device__ __forceinline__ void async16(const void* g, void* l) {
    __builtin_amdgcn_global_load_lds(
        (const __attribute__((address_space(1))) unsigned int*)(uintptr_t)g,
        (__attribute__((address_space(3))) unsigned int*)(unsigned int)(uintptr_t)l,
        16, 0, 0);
}

// ---------------- cvt: fp32 -> bf16 row-major copies -------------------------
__global__ void cvt_kernel(const float* __restrict__ obs, const float* __restrict__ W1,
                           const float* __restrict__ W2, const float* __restrict__ W3,
                           unsigned short* __restrict__ obs_bf, unsigned short* __restrict__ W1Cbf,
                           unsigned short* __restrict__ W2bf, unsigned short* __restrict__ W3bf) {
    const int e = (blockIdx.x * 256 + threadIdx.x) * 4;   // 2424832 elems
    const float* src; unsigned short* dst;
    if (e < 65536)        { src = obs + e; dst = obs_bf + e; }
    else if (e < 458752)  { int f = e - 65536; int i = f >> 16; int rem = f & 65535;
                            src = W1 + (size_t)(i + 1) * 328192 + 513*512 + rem; dst = W1Cbf + f; }
    else if (e < 2031616) { int f = e - 458752; src = W2 + 262144 + f; dst = W2bf + f; }
    else                  { int f = e - 2031616; src = W3 + 65536 + f; dst = W3bf + f; }
    float4 v = *(const float4*)src;
    u16x4 o; o[0] = f2bf(v.x); o[1] = f2bf(v.y); o[2] = f2bf(v.z); o[3] = f2bf(v.w);
    *(u16x4*)dst = o;
}

// ---------------- transpose+convert: W1AT / W2T ------------------------------
__global__ void prep_transpose(const float* __restrict__ W1, const float* __restrict__ W2,
                               unsigned short* __restrict__ W1AT, unsigned short* __restrict__ W2T) {
    __shared__ float tile[32][33];
    const int z = blockIdx.z;
    const float* ip; unsigned short* op;
    if (z < 6) { ip = W1 + (size_t)(z + 1) * 328192; op = W1AT + (size_t)z * 262144; }
    else       { int i = z - 6; ip = W2 + (size_t)(i + 1) * 262144; op = W2T + (size_t)i * 262144; }
    const int r0 = blockIdx.x * 32, c0 = blockIdx.y * 32;
    const int tx = threadIdx.x, ty = threadIdx.y;  // 32 x 8
    #pragma unroll
    for (int j = 0; j < 32; j += 8)
        tile[ty + j][tx] = ip[(size_t)(r0 + ty + j) * 512 + c0 + tx];
    __syncthreads();
    #pragma unroll
    for (int j = 0; j < 32; j += 8)
        op[(size_t)(c0 + ty + j) * 512 + r0 + tx] = f2bf(tile[tx][ty + j]);
}

// ---------------- vq: v[z][k] = W3[z+1][k][:]·Wp  (fp32) ---------------------
__global__ void vq_kernel(const float* __restrict__ W3, const float* __restrict__ Wp,
                          float* __restrict__ vq) {
    const int z = blockIdx.x, k = threadIdx.x;   // 6 x 512
    const float4* row = (const float4*)(W3 + (size_t)(z + 1) * 65536 + (size_t)k * 128);
    const float4* wp4 = (const float4*)Wp;
    float s = 0.f;
    #pragma unroll 8
    for (int n = 0; n < 32; ++n) {
        float4 a = row[n], w = wp4[n];
        s += a.x*w.x + a.y*w.y + a.z*w.z + a.w*w.w;
    }
    vq[z * 512 + k] = s;
}

// ---------------- Yobs[z][b][h] = obs@W1A[z+1] + b1[z+1] ---------------------
__launch_bounds__(256)
__global__ void yobs_kernel(const unsigned short* __restrict__ A,      // obs_bf [128][512]
                            const unsigned short* __restrict__ BtAll,  // W1AT [6][512][512]
                            const float* __restrict__ b1,
                            float* __restrict__ Yobs) {
    __shared__ unsigned short As[64*32];
    __shared__ unsigned short Bs[128*32];
    const int m0 = blockIdx.x * 64;
    const int n0 = blockIdx.y * 128;
    const int z  = blockIdx.z;
    const unsigned short* Bt = BtAll + (size_t)z * 262144;
    const int tid = threadIdx.x, lane = tid & 63, wave = tid >> 6;
    const int wm = wave >> 1, wn = wave & 1;
    const int srow = tid >> 2, skc = (tid & 3) * 8;
    const unsigned short* gA  = A  + (size_t)(m0 + srow) * HID + skc;
    const unsigned short* gB0 = Bt + (size_t)(n0 + srow) * HID + skc;
    const unsigned short* gB1 = gB0 + 64 * HID;
    f32x4 acc[2][4] = {};
    for (int k0 = 0; k0 < HID; k0 += 32) {
        async16(gA + k0, As + tid*8);
        async16(gB0 + k0, Bs + tid*8);
        async16(gB1 + k0, Bs + 2048 + tid*8);
        __syncthreads();
        const int q8 = (lane >> 4) * 8, l15 = lane & 15;
        bf16x8 af[2], bfr[4];
        #pragma unroll
        for (int mt = 0; mt < 2; ++mt)
            af[mt] = *(const bf16x8*)(As + (wm*32 + mt*16 + l15) * 32 + q8);
        #pragma unroll
        for (int nt = 0; nt < 4; ++nt)
            bfr[nt] = *(const bf16x8*)(Bs + (wn*64 + nt*16 + l15) * 32 + q8);
        #pragma unroll
        for (int mt = 0; mt < 2; ++mt)
            #pragma unroll
            for (int nt = 0; nt < 4; ++nt)
                acc[mt][nt] = __builtin_amdgcn_mfma_f32_16x16x32_bf16(af[mt], bfr[nt], acc[mt][nt], 0, 0, 0);
        __syncthreads();
    }
    const int colL = wn*64 + (lane & 15);
    #pragma unroll
    for (int nt = 0; nt < 4; ++nt) {
        const int col = n0 + colL + nt*16;
        const float bb = b1[(z + 1) * HID + col];
        #pragma unroll
        for (int mt = 0; mt < 2; ++mt)
            #pragma unroll
            for (int r = 0; r < 4; ++r) {
                const int row = m0 + wm*32 + mt*16 + (lane >> 4)*4 + r;
                Yobs[(size_t)z * 65536 + (size_t)row * HID + col] = acc[mt][nt][r] + bb;
            }
    }
}

// ---------------- chain: serial context chain + QOFF precompute --------------
// QOFF[(i-1)*128+b] = dot(ctx_in + b3[i], Wp) + bp
__launch_bounds__(1024)
__global__ void chain_kernel(const float* __restrict__ Yobs, const float* __restrict__ W1,
                             const unsigned short* __restrict__ W1Cbf,
                             const unsigned short* __restrict__ W2bf,
                             const unsigned short* __restrict__ W3bf,
                             const float* __restrict__ b2, const float* __restrict__ b3,
                             const float* __restrict__ actions,
                             const float* __restrict__ Wp, const float* __restrict__ bp,
                             float* __restrict__ Y0all, float* __restrict__ QOFF) {
    const int b = blockIdx.x, t = threadIdx.x;
    __shared__ float ctx[128], h1[512], h2s[512];
    __shared__ float part[2048];
    const int pair = t & 255, kq = t >> 8;
    const int pair3 = t & 63, kq3 = t >> 6;
    if (t < 128) ctx[t] = 0.f;
    __syncthreads();
    for (int i = 1; i <= 6; ++i) {
        if (t < 128) part[t] = (ctx[t] + b3[i*128 + t]) * Wp[t];
        __syncthreads();
        if (t < 64) {
            float v = part[t] + part[t + 64];
            #pragma unroll
            for (int o = 32; o > 0; o >>= 1) v += __shfl_down(v, o, 64);
            if (t == 0) QOFF[(i-1)*128 + b] = v + bp[0];
        }
        __syncthreads();
        const float a = actions[b*ACT + i];
        float fj = floorf((a + 1.0f) * 50.0f);
        fj = fminf(fmaxf(fj, 0.0f), 99.0f);
        // ---- layer1 ctx part ----
        {
            const unsigned int* wp1 = (const unsigned int*)(W1Cbf + (size_t)(i-1)*65536) + pair;
            float acc0 = 0.f, acc1 = 0.f;
            #pragma unroll 8
            for (int k = kq*32; k < kq*32 + 32; ++k) {
                unsigned int u = wp1[k*256];
                float c = ctx[k];
                acc0 = fmaf(c, __uint_as_float(u << 16), acc0);
                acc1 = fmaf(c, __uint_as_float(u & 0xffff0000u), acc1);
            }
            *(float2*)(&part[kq*512 + 2*pair]) = make_float2(acc0, acc1);
        }
        __syncthreads();
        if (t < 256) {
            const int n2 = 2*t;
            float2 p0 = *(const float2*)(&part[n2]);
            float2 p1 = *(const float2*)(&part[512 + n2]);
            float2 p2 = *(const float2*)(&part[1024 + n2]);
            float2 p3 = *(const float2*)(&part[1536 + n2]);
            float2 yo = *(const float2*)(Yobs + (size_t)(i-1)*65536 + b*512 + n2);
            float y0a = yo.x + p0.x + p1.x + p2.x + p3.x;
            float y0b = yo.y + p0.y + p1.y + p2.y + p3.y;
            *(float2*)(Y0all + (size_t)(i-1)*65536 + b*512 + n2) = make_float2(y0a, y0b);
            const float* w1a = W1 + (size_t)i*328192 + 262144;
            float2 wv = *(const float2*)(w1a + n2);
            h1[n2]   = fmaxf(fmaf(fj, wv.x, y0a), 0.f);
            h1[n2+1] = fmaxf(fmaf(fj, wv.y, y0b), 0.f);
        }
        __syncthreads();
        // ---- layer2 ----
        {
            const unsigned int* wp2 = (const unsigned int*)(W2bf + (size_t)(i-1)*262144) + pair;
            float acc0 = 0.f, acc1 = 0.f;
            #pragma unroll 16
            for (int k = kq*128; k < kq*128 + 128; ++k) {
                unsigned int u = wp2[k*256];
                float hv = h1[k];
                acc0 = fmaf(hv, __uint_as_float(u << 16), acc0);
                acc1 = fmaf(hv, __uint_as_float(u & 0xffff0000u), acc1);
            }
            *(float2*)(&part[kq*512 + 2*pair]) = make_float2(acc0, acc1);
        }
        __syncthreads();
        if (t < 256) {
            const int n2 = 2*t;
            float2 p0 = *(const float2*)(&part[n2]);
            float2 p1 = *(const float2*)(&part[512 + n2]);
            float2 p2 = *(const float2*)(&part[1024 + n2]);
            float2 p3 = *(const float2*)(&part[1536 + n2]);
            float2 bb = *(const float2*)(b2 + i*512 + n2);
            h2s[n2]   = fmaxf(p0.x + p1.x + p2.x + p3.x + bb.x, 0.f);
            h2s[n2+1] = fmaxf(p0.y + p1.y + p2.y + p3.y + bb.y, 0.f);
        }
        __syncthreads();
        // ---- layer3 ----
        {
            const unsigned int* wp3 = (const unsigned int*)(W3bf + (size_t)(i-1)*65536) + pair3;
            float acc0 = 0.f, acc1 = 0.f;
            #pragma unroll 8
            for (int k = kq3*32; k < kq3*32 + 32; ++k) {
                unsigned int u = wp3[k*64];
                float hv = h2s[k];
                acc0 = fmaf(hv, __uint_as_float(u << 16), acc0);
                acc1 = fmaf(hv, __uint_as_float(u & 0xffff0000u), acc1);
            }
            *(float2*)(&part[kq3*128 + 2*pair3]) = make_float2(acc0, acc1);
        }
        __syncthreads();
        if (t < 128) {
            float s = 0.f;
            #pragma unroll
            for (int qg = 0; qg < 16; ++qg) s += part[qg*128 + t];
            ctx[t] = s + b3[i*128 + t] + ctx[t];
        }
        __syncthreads();
    }
}

// ---------------- h1all: H1[row][k] = bf16(relu(Y0+c*w1a)), 76800 rows -------
__global__ void h1all_kernel(const float* __restrict__ Y0all, const float* __restrict__ W1,
                             unsigned short* __restrict__ H1) {
    const int t = blockIdx.x * 256 + threadIdx.x;   // 76800*64 threads
    const int row = t >> 6, kc = (t & 63) << 3;
    const int z = row / 12800, rr = row - z * 12800;
    const int b = rr / 100;
    const float c = (float)(rr - b * 100);
    const float* yp = Y0all + (size_t)z*65536 + (size_t)b*512 + kc;
    const float* wp = W1 + (size_t)(z+1)*328192 + 262144 + kc;
    float4 ya = *(const float4*)(yp), yb = *(const float4*)(yp + 4);
    float4 wa = *(const float4*)(wp), wb = *(const float4*)(wp + 4);
    uint4 o;
    o.x = pack2bf(fmaxf(fmaf(c, wa.x, ya.x), 0.f), fmaxf(fmaf(c, wa.y, ya.y), 0.f));
    o.y = pack2bf(fmaxf(fmaf(c, wa.z, ya.z), 0.f), fmaxf(fmaf(c, wa.w, ya.w), 0.f));
    o.z = pack2bf(fmaxf(fmaf(c, wb.x, yb.x), 0.f), fmaxf(fmaf(c, wb.y, yb.y), 0.f));
    o.w = pack2bf(fmaxf(fmaf(c, wb.z, yb.z), 0.f), fmaxf(fmaf(c, wb.w, yb.w), 0.f));
    *(uint4*)(H1 + (size_t)row * 512 + kc) = o;
}

// ---------------- gemm2q: LDS-staged GEMM (async16 A+B) + v-dot epilogue -----
// qpart[plane2][row] = sum_col relu((H1@W2)[row,col]+b2[col]) * v[col] partials
// grid (4, 600): 4 N-planes of one row-tile adjacent -> H1 tile L2-shared.
__launch_bounds__(256)
__global__ void gemm2q_kernel(const unsigned short* __restrict__ H1,
                              const unsigned short* __restrict__ W2T,
                              const float* __restrict__ b2,
                              const float* __restrict__ vq, float* __restrict__ qpart) {
    __shared__ unsigned short As[2][4096];
    __shared__ unsigned short Bs[2][4096];
    const int plane = blockIdx.x;            // 0..3
    const int rt = blockIdx.y;               // 0..599
    const int z  = rt / 100;
    const int r0 = rt * 128;                 // global row
    const int n0 = plane * 128;
    const int tid = threadIdx.x, lane = tid & 63, wave = tid >> 6;
    const int wm = wave >> 1, wn = wave & 1;
    const int srow = tid >> 2, skc = (tid & 3) * 8;
    const int l15 = lane & 15, q8 = (lane >> 4) * 8;
    const unsigned short* gA0 = H1 + (size_t)(r0 + srow)*512 + skc;
    const unsigned short* gA1 = gA0 + 64*512;
    const unsigned short* gB0 = W2T + (size_t)z*262144 + (size_t)(n0 + srow)*512 + skc;
    const unsigned short* gB1 = gB0 + 64*512;
    f32x4 acc[4][4] = {};
    for (int k0 = 0; k0 < 512; k0 += 64) {
        async16(gA0 + k0,      &As[0][tid*8]);
        async16(gA1 + k0,      &As[0][2048 + tid*8]);
        async16(gA0 + k0 + 32, &As[1][tid*8]);
        async16(gA1 + k0 + 32, &As[1][2048 + tid*8]);
        async16(gB0 + k0,      &Bs[0][tid*8]);
        async16(gB1 + k0,      &Bs[0][2048 + tid*8]);
        async16(gB0 + k0 + 32, &Bs[1][tid*8]);
        async16(gB1 + k0 + 32, &Bs[1][2048 + tid*8]);
        __syncthreads();
        #pragma unroll
        for (int h = 0; h < 2; ++h) {
            bf16x8 af[4], bfr[4];
            #pragma unroll
            for (int mt = 0; mt < 4; ++mt)
                af[mt] = *(const bf16x8*)(&As[h][(wm*64 + mt*16 + l15)*32 + q8]);
            #pragma unroll
            for (int nt = 0; nt < 4; ++nt)
                bfr[nt] = *(const bf16x8*)(&Bs[h][(wn*64 + nt*16 + l15)*32 + q8]);
            #pragma unroll
            for (int mt = 0; mt < 4; ++mt)
                #pragma unroll
                for (int nt = 0; nt < 4; ++nt)
                    acc[mt][nt] = __builtin_amdgcn_mfma_f32_16x16x32_bf16(af[mt], bfr[nt], acc[mt][nt], 0, 0, 0);
        }
        __syncthreads();
    }
    // epilogue: p = sum_nt relu(acc + b2[col]) * v[col]; reduce over l15; store
    float vb[4], bb[4];
    #pragma unroll
    for (int nt = 0; nt < 4; ++nt) {
        const int col = n0 + wn*64 + nt*16 + l15;
        bb[nt] = b2[(z+1)*512 + col];
        vb[nt] = vq[z*512 + col];
    }
    const int plane2 = plane * 2 + wn;       // 0..7
    const int gq = lane >> 4;
    #pragma unroll
    for (int mt = 0; mt < 4; ++mt)
        #pragma unroll
        for (int r = 0; r < 4; ++r) {
            float p = 0.f;
            #pragma unroll
            for (int nt = 0; nt < 4; ++nt)
                p = fmaf(fmaxf(acc[mt][nt][r] + bb[nt], 0.f), vb[nt], p);
            p += __shfl_xor(p, 1, 64);
            p += __shfl_xor(p, 2, 64);
            p += __shfl_xor(p, 4, 64);
            p += __shfl_xor(p, 8, 64);
            if (l15 == 0) {
                const int grow = r0 + wm*64 + mt*16 + gq*4 + r;
                qpart[(size_t)plane2 * 76800 + grow] = p;
            }
        }
}

// ---------------- lse: out[b] = logsumexp([q[b,0:600], zeros(100)]) ----------
__global__ void lse_kernel(const float* __restrict__ qpart, const float* __restrict__ QOFF,
                           float* __restrict__ out) {
    __shared__ float red[256];
    __shared__ float qs[QW];
    const int b = blockIdx.x, t = threadIdx.x;
    for (int k = t; k < QW; k += 256) {
        const int z = k / 100, gc = k - z * 100;
        const int grow = z * 12800 + b * 100 + gc;
        float s = QOFF[z * 128 + b];
        #pragma unroll
        for (int p = 0; p < 8; ++p) s += qpart[(size_t)p * 76800 + grow];
        qs[k] = s;
    }
    __syncthreads();
    float m = 0.0f;   // zero tail participates in the max
    for (int k = t; k < QW; k += 256) m = fmaxf(m, qs[k]);
    red[t] = m; __syncthreads();
    for (int s = 128; s > 0; s >>= 1) { if (t < s) red[t] = fmaxf(red[t], red[t+s]); __syncthreads(); }
    m = red[0]; __syncthreads();
    float sum = 0.0f;
    for (int k = t; k < QW; k += 256) sum += expf(qs[k] - m);
    red[t] = sum; __syncthreads();
    for (int s = 128; s > 0; s >>= 1) { if (t < s) red[t] += red[t+s]; __syncthreads(); }
    if (t == 0) out[b] = logf(red[0] + 100.0f * expf(-m)) + m;
}

extern "C" void kernel_launch(void* const* d_in, const int* in_sizes, int n_in,
                              void* d_out, int out_size, void* d_ws, size_t ws_size,
                              hipStream_t stream) {
    const float* obs     = (const float*)d_in[0];
    const float* actions = (const float*)d_in[1];
    const float* W1      = (const float*)d_in[2];
    const float* b1      = (const float*)d_in[3];
    const float* W2      = (const float*)d_in[4];
    const float* b2      = (const float*)d_in[5];
    const float* W3      = (const float*)d_in[6];
    const float* b3      = (const float*)d_in[7];
    const float* Wp      = (const float*)d_in[8];
    const float* bp      = (const float*)d_in[9];
    float* out = (float*)d_out;
    float* ws  = (float*)d_ws;

    // workspace layout (float offsets)
    unsigned short* obs_bf = (unsigned short*)(ws);            // 32768 f
    unsigned short* W1AT   = (unsigned short*)(ws + 32768);    // 786432 f
    unsigned short* W2T    = (unsigned short*)(ws + 819200);   // 786432 f
    unsigned short* W1Cbf  = (unsigned short*)(ws + 1605632);  // 196608 f
    unsigned short* W2bf   = (unsigned short*)(ws + 1802240);  // 786432 f
    unsigned short* W3bf   = (unsigned short*)(ws + 2588672);  // 196608 f
    float* Yobs  = ws + 2785280;                               // 393216 f
    float* Y0all = ws + 3178496;                               // 393216 f
    float* QOFF  = ws + 3571712;                               // 1024 f
    float* vq    = ws + 3572736;                               // 3072 f
    float* qpart = ws + 3575808;                               // 614400 f
    unsigned short* H1 = (unsigned short*)(ws + 4190208);      // 19660800 f

    cvt_kernel<<<2368, 256, 0, stream>>>(obs, W1, W2, W3, obs_bf, W1Cbf, W2bf, W3bf);
    prep_transpose<<<dim3(16,16,12), dim3(32,8), 0, stream>>>(W1, W2, W1AT, W2T);
    vq_kernel<<<6, 512, 0, stream>>>(W3, Wp, vq);
    yobs_kernel<<<dim3(2,4,6), 256, 0, stream>>>(obs_bf, W1AT, b1, Yobs);
    chain_kernel<<<BATCH, 1024, 0, stream>>>(Yobs, W1, W1Cbf, W2bf, W3bf, b2, b3, actions, Wp, bp, Y0all, QOFF);
    h1all_kernel<<<19200, 256, 0, stream>>>(Y0all, W1, H1);
    gemm2q_kernel<<<dim3(4, 600), 256, 0, stream>>>(H1, W2T, b2, vq, qpart);
    lse_kernel<<<BATCH, 256, 0, stream>>>(qpart, QOFF, out);
}

// Round 12
// 234.459 us; speedup vs baseline: 1.0605x; 1.0605x over previous
//
#include <hip/hip_runtime.h>
#include <math.h>

#define BATCH 128
#define ACT 7
#define NC 100
#define CTXD 128
#define HID 512
#define QW 600               // q cols 600..699 of reference are exactly 0

typedef __attribute__((ext_vector_type(8))) __bf16 bf16x8;
typedef __attribute__((ext_vector_type(4))) float f32x4;
typedef __attribute__((ext_vector_type(4))) unsigned short u16x4;

__device__ __forceinline__ unsigned short f2bf(float f) {
    union { float f; unsigned int u; } v; v.f = f;
    unsigned int u = v.u;
    return (unsigned short)((u + 0x7fffu + ((u >> 16) & 1u)) >> 16);
}
__device__ __forceinline__ unsigned int pack2bf(float a, float b) {
    unsigned int ua = __float_as_uint(a) + 0x8000u;
    unsigned int ub = __float_as_uint(b) + 0x8000u;
    return (ua >> 16) | (ub & 0xffff0000u);
}

__device__ __forceinline__ void async16(const void* g, void* l) {
    __builtin_amdgcn_global_load_lds(
        (const __attribute__((address_space(1))) unsigned int*)(uintptr_t)g,
        (__attribute__((address_space(3))) unsigned int*)(unsigned int)(uintptr_t)l,
        16, 0, 0);
}

// ---------------- prep: cvt copies + transposes + vq in ONE launch -----------
// b in [0,2368): bf16 row-major copies (obs, W1C, W2, W3)
// b in [2368,5440): 32x32 transpose tiles for W1AT / W2T
// b in [5440,5452): vq[z][k] = W3[z+1][k][:]·Wp
__global__ void prep_kernel(const float* __restrict__ obs, const float* __restrict__ W1,
                            const float* __restrict__ W2, const float* __restrict__ W3,
                            const float* __restrict__ Wp,
                            unsigned short* __restrict__ obs_bf, unsigned short* __restrict__ W1Cbf,
                            unsigned short* __restrict__ W2bf, unsigned short* __restrict__ W3bf,
                            unsigned short* __restrict__ W1AT, unsigned short* __restrict__ W2T,
                            float* __restrict__ vq) {
    const int bidx = blockIdx.x, tid = threadIdx.x;
    if (bidx < 2368) {
        const int e = (bidx * 256 + tid) * 4;   // 2424832 elems
        const float* src; unsigned short* dst;
        if (e < 65536)        { src = obs + e; dst = obs_bf + e; }
        else if (e < 458752)  { int f = e - 65536; int i = f >> 16; int rem = f & 65535;
                                src = W1 + (size_t)(i + 1) * 328192 + 513*512 + rem; dst = W1Cbf + f; }
        else if (e < 2031616) { int f = e - 458752; src = W2 + 262144 + f; dst = W2bf + f; }
        else                  { int f = e - 2031616; src = W3 + 65536 + f; dst = W3bf + f; }
        float4 v = *(const float4*)src;
        u16x4 o; o[0] = f2bf(v.x); o[1] = f2bf(v.y); o[2] = f2bf(v.z); o[3] = f2bf(v.w);
        *(u16x4*)dst = o;
    } else if (bidx < 5440) {
        __shared__ float tile[32][33];
        const int idx = bidx - 2368;            // 0..3071
        const int z = idx >> 8, rem = idx & 255;
        const int rb = rem & 15, cb = rem >> 4;
        const float* ip; unsigned short* op;
        if (z < 6) { ip = W1 + (size_t)(z + 1) * 328192; op = W1AT + (size_t)z * 262144; }
        else       { int i = z - 6; ip = W2 + (size_t)(i + 1) * 262144; op = W2T + (size_t)i * 262144; }
        const int r0 = rb * 32, c0 = cb * 32;
        const int tx = tid & 31, ty = tid >> 5;  // 32 x 8
        #pragma unroll
        for (int j = 0; j < 32; j += 8)
            tile[ty + j][tx] = ip[(size_t)(r0 + ty + j) * 512 + c0 + tx];
        __syncthreads();
        #pragma unroll
        for (int j = 0; j < 32; j += 8)
            op[(size_t)(c0 + ty + j) * 512 + r0 + tx] = f2bf(tile[tx][ty + j]);
    } else {
        const int idx = bidx - 5440;            // 0..11
        const int z = idx >> 1, k = (idx & 1) * 256 + tid;
        const float4* row = (const float4*)(W3 + (size_t)(z + 1) * 65536 + (size_t)k * 128);
        const float4* wp4 = (const float4*)Wp;
        float s = 0.f;
        #pragma unroll 8
        for (int n = 0; n < 32; ++n) {
            float4 a = row[n], w = wp4[n];
            s += a.x*w.x + a.y*w.y + a.z*w.z + a.w*w.w;
        }
        vq[z * 512 + k] = s;
    }
}

// ---------------- Yobs[z][b][h] = obs@W1A[z+1] + b1[z+1] ---------------------
__launch_bounds__(256)
__global__ void yobs_kernel(const unsigned short* __restrict__ A,      // obs_bf [128][512]
                            const unsigned short* __restrict__ BtAll,  // W1AT [6][512][512]
                            const float* __restrict__ b1,
                            float* __restrict__ Yobs) {
    __shared__ unsigned short As[64*32];
    __shared__ unsigned short Bs[128*32];
    const int m0 = blockIdx.x * 64;
    const int n0 = blockIdx.y * 128;
    const int z  = blockIdx.z;
    const unsigned short* Bt = BtAll + (size_t)z * 262144;
    const int tid = threadIdx.x, lane = tid & 63, wave = tid >> 6;
    const int wm = wave >> 1, wn = wave & 1;
    const int srow = tid >> 2, skc = (tid & 3) * 8;
    const unsigned short* gA  = A  + (size_t)(m0 + srow) * HID + skc;
    const unsigned short* gB0 = Bt + (size_t)(n0 + srow) * HID + skc;
    const unsigned short* gB1 = gB0 + 64 * HID;
    f32x4 acc[2][4] = {};
    for (int k0 = 0; k0 < HID; k0 += 32) {
        async16(gA + k0, As + tid*8);
        async16(gB0 + k0, Bs + tid*8);
        async16(gB1 + k0, Bs + 2048 + tid*8);
        __syncthreads();
        const int q8 = (lane >> 4) * 8, l15 = lane & 15;
        bf16x8 af[2], bfr[4];
        #pragma unroll
        for (int mt = 0; mt < 2; ++mt)
            af[mt] = *(const bf16x8*)(As + (wm*32 + mt*16 + l15) * 32 + q8);
        #pragma unroll
        for (int nt = 0; nt < 4; ++nt)
            bfr[nt] = *(const bf16x8*)(Bs + (wn*64 + nt*16 + l15) * 32 + q8);
        #pragma unroll
        for (int mt = 0; mt < 2; ++mt)
            #pragma unroll
            for (int nt = 0; nt < 4; ++nt)
                acc[mt][nt] = __builtin_amdgcn_mfma_f32_16x16x32_bf16(af[mt], bfr[nt], acc[mt][nt], 0, 0, 0);
        __syncthreads();
    }
    const int colL = wn*64 + (lane & 15);
    #pragma unroll
    for (int nt = 0; nt < 4; ++nt) {
        const int col = n0 + colL + nt*16;
        const float bb = b1[(z + 1) * HID + col];
        #pragma unroll
        for (int mt = 0; mt < 2; ++mt)
            #pragma unroll
            for (int r = 0; r < 4; ++r) {
                const int row = m0 + wm*32 + mt*16 + (lane >> 4)*4 + r;
                Yobs[(size_t)z * 65536 + (size_t)row * HID + col] = acc[mt][nt][r] + bb;
            }
    }
}

// ---------------- chain: serial context chain + QOFF precompute --------------
__launch_bounds__(1024)
__global__ void chain_kernel(const float* __restrict__ Yobs, const float* __restrict__ W1,
                             const unsigned short* __restrict__ W1Cbf,
                             const unsigned short* __restrict__ W2bf,
                             const unsigned short* __restrict__ W3bf,
                             const float* __restrict__ b2, const float* __restrict__ b3,
                             const float* __restrict__ actions,
                             const float* __restrict__ Wp, const float* __restrict__ bp,
                             float* __restrict__ Y0all, float* __restrict__ QOFF) {
    const int b = blockIdx.x, t = threadIdx.x;
    __shared__ float ctx[128], h1[512], h2s[512];
    __shared__ float part[2048];
    const int pair = t & 255, kq = t >> 8;
    const int pair3 = t & 63, kq3 = t >> 6;
    if (t < 128) ctx[t] = 0.f;
    __syncthreads();
    for (int i = 1; i <= 6; ++i) {
        if (t < 128) part[t] = (ctx[t] + b3[i*128 + t]) * Wp[t];
        __syncthreads();
        if (t < 64) {
            float v = part[t] + part[t + 64];
            #pragma unroll
            for (int o = 32; o > 0; o >>= 1) v += __shfl_down(v, o, 64);
            if (t == 0) QOFF[(i-1)*128 + b] = v + bp[0];
        }
        __syncthreads();
        const float a = actions[b*ACT + i];
        float fj = floorf((a + 1.0f) * 50.0f);
        fj = fminf(fmaxf(fj, 0.0f), 99.0f);
        // ---- layer1 ctx part ----
        {
            const unsigned int* wp1 = (const unsigned int*)(W1Cbf + (size_t)(i-1)*65536) + pair;
            float acc0 = 0.f, acc1 = 0.f;
            #pragma unroll 8
            for (int k = kq*32; k < kq*32 + 32; ++k) {
                unsigned int u = wp1[k*256];
                float c = ctx[k];
                acc0 = fmaf(c, __uint_as_float(u << 16), acc0);
                acc1 = fmaf(c, __uint_as_float(u & 0xffff0000u), acc1);
            }
            *(float2*)(&part[kq*512 + 2*pair]) = make_float2(acc0, acc1);
        }
        __syncthreads();
        if (t < 256) {
            const int n2 = 2*t;
            float2 p0 = *(const float2*)(&part[n2]);
            float2 p1 = *(const float2*)(&part[512 + n2]);
            float2 p2 = *(const float2*)(&part[1024 + n2]);
            float2 p3 = *(const float2*)(&part[1536 + n2]);
            float2 yo = *(const float2*)(Yobs + (size_t)(i-1)*65536 + b*512 + n2);
            float y0a = yo.x + p0.x + p1.x + p2.x + p3.x;
            float y0b = yo.y + p0.y + p1.y + p2.y + p3.y;
            *(float2*)(Y0all + (size_t)(i-1)*65536 + b*512 + n2) = make_float2(y0a, y0b);
            const float* w1a = W1 + (size_t)i*328192 + 262144;
            float2 wv = *(const float2*)(w1a + n2);
            h1[n2]   = fmaxf(fmaf(fj, wv.x, y0a), 0.f);
            h1[n2+1] = fmaxf(fmaf(fj, wv.y, y0b), 0.f);
        }
        __syncthreads();
        // ---- layer2 ----
        {
            const unsigned int* wp2 = (const unsigned int*)(W2bf + (size_t)(i-1)*262144) + pair;
            float acc0 = 0.f, acc1 = 0.f;
            #pragma unroll 16
            for (int k = kq*128; k < kq*128 + 128; ++k) {
                unsigned int u = wp2[k*256];
                float hv = h1[k];
                acc0 = fmaf(hv, __uint_as_float(u << 16), acc0);
                acc1 = fmaf(hv, __uint_as_float(u & 0xffff0000u), acc1);
            }
            *(float2*)(&part[kq*512 + 2*pair]) = make_float2(acc0, acc1);
        }
        __syncthreads();
        if (t < 256) {
            const int n2 = 2*t;
            float2 p0 = *(const float2*)(&part[n2]);
            float2 p1 = *(const float2*)(&part[512 + n2]);
            float2 p2 = *(const float2*)(&part[1024 + n2]);
            float2 p3 = *(const float2*)(&part[1536 + n2]);
            float2 bb = *(const float2*)(b2 + i*512 + n2);
            h2s[n2]   = fmaxf(p0.x + p1.x + p2.x + p3.x + bb.x, 0.f);
            h2s[n2+1] = fmaxf(p0.y + p1.y + p2.y + p3.y + bb.y, 0.f);
        }
        __syncthreads();
        // ---- layer3 ----
        {
            const unsigned int* wp3 = (const unsigned int*)(W3bf + (size_t)(i-1)*65536) + pair3;
            float acc0 = 0.f, acc1 = 0.f;
            #pragma unroll 8
            for (int k = kq3*32; k < kq3*32 + 32; ++k) {
                unsigned int u = wp3[k*64];
                float hv = h2s[k];
                acc0 = fmaf(hv, __uint_as_float(u << 16), acc0);
                acc1 = fmaf(hv, __uint_as_float(u & 0xffff0000u), acc1);
            }
            *(float2*)(&part[kq3*128 + 2*pair3]) = make_float2(acc0, acc1);
        }
        __syncthreads();
        if (t < 128) {
            float s = 0.f;
            #pragma unroll
            for (int qg = 0; qg < 16; ++qg) s += part[qg*128 + t];
            ctx[t] = s + b3[i*128 + t] + ctx[t];
        }
        __syncthreads();
    }
}

// ---------------- h1all: H1[row][k] = bf16(relu(Y0+c*w1a)), 76800 rows -------
__global__ void h1all_kernel(const float* __restrict__ Y0all, const float* __restrict__ W1,
                             unsigned short* __restrict__ H1) {
    const int t = blockIdx.x * 256 + threadIdx.x;   // 76800*64 threads
    const int row = t >> 6, kc = (t & 63) << 3;
    const int z = row / 12800, rr = row - z * 12800;
    const int b = rr / 100;
    const float c = (float)(rr - b * 100);
    const float* yp = Y0all + (size_t)z*65536 + (size_t)b*512 + kc;
    const float* wp = W1 + (size_t)(z+1)*328192 + 262144 + kc;
    float4 ya = *(const float4*)(yp), yb = *(const float4*)(yp + 4);
    float4 wa = *(const float4*)(wp), wb = *(const float4*)(wp + 4);
    uint4 o;
    o.x = pack2bf(fmaxf(fmaf(c, wa.x, ya.x), 0.f), fmaxf(fmaf(c, wa.y, ya.y), 0.f));
    o.y = pack2bf(fmaxf(fmaf(c, wa.z, ya.z), 0.f), fmaxf(fmaf(c, wa.w, ya.w), 0.f));
    o.z = pack2bf(fmaxf(fmaf(c, wb.x, yb.x), 0.f), fmaxf(fmaf(c, wb.y, yb.y), 0.f));
    o.w = pack2bf(fmaxf(fmaf(c, wb.z, yb.z), 0.f), fmaxf(fmaf(c, wb.w, yb.w), 0.f));
    *(uint4*)(H1 + (size_t)row * 512 + kc) = o;
}

// ---------------- gemm2q: XCD-swizzled LDS GEMM + v-dot epilogue -------------
// Grid 2400 1-D. xcd = b&7, seq = b>>3, plane = seq&3, rt = xcd*75 + (seq>>2).
// All 4 planes of row-tile rt share one XCD's L2 -> H1 tile fetched once.
__launch_bounds__(256)
__global__ void gemm2q_kernel(const unsigned short* __restrict__ H1,
                              const unsigned short* __restrict__ W2T,
                              const float* __restrict__ b2,
                              const float* __restrict__ vq, float* __restrict__ qpart) {
    __shared__ unsigned short As[2][4096];
    __shared__ unsigned short Bs[2][4096];
    const int bidx = blockIdx.x;             // 0..2399
    const int xcd = bidx & 7, seq = bidx >> 3;
    const int plane = seq & 3;
    const int rt = xcd * 75 + (seq >> 2);    // 0..599
    const int z  = rt / 100;
    const int r0 = rt * 128;                 // global row
    const int n0 = plane * 128;
    const int tid = threadIdx.x, lane = tid & 63, wave = tid >> 6;
    const int wm = wave >> 1, wn = wave & 1;
    const int srow = tid >> 2, skc = (tid & 3) * 8;
    const int l15 = lane & 15, q8 = (lane >> 4) * 8;
    const unsigned short* gA0 = H1 + (size_t)(r0 + srow)*512 + skc;
    const unsigned short* gA1 = gA0 + 64*512;
    const unsigned short* gB0 = W2T + (size_t)z*262144 + (size_t)(n0 + srow)*512 + skc;
    const unsigned short* gB1 = gB0 + 64*512;
    f32x4 acc[4][4] = {};
    for (int k0 = 0; k0 < 512; k0 += 64) {
        async16(gA0 + k0,      &As[0][tid*8]);
        async16(gA1 + k0,      &As[0][2048 + tid*8]);
        async16(gA0 + k0 + 32, &As[1][tid*8]);
        async16(gA1 + k0 + 32, &As[1][2048 + tid*8]);
        async16(gB0 + k0,      &Bs[0][tid*8]);
        async16(gB1 + k0,      &Bs[0][2048 + tid*8]);
        async16(gB0 + k0 + 32, &Bs[1][tid*8]);
        async16(gB1 + k0 + 32, &Bs[1][2048 + tid*8]);
        __syncthreads();
        #pragma unroll
        for (int h = 0; h < 2; ++h) {
            bf16x8 af[4], bfr[4];
            #pragma unroll
            for (int mt = 0; mt < 4; ++mt)
                af[mt] = *(const bf16x8*)(&As[h][(wm*64 + mt*16 + l15)*32 + q8]);
            #pragma unroll
            for (int nt = 0; nt < 4; ++nt)
                bfr[nt] = *(const bf16x8*)(&Bs[h][(wn*64 + nt*16 + l15)*32 + q8]);
            #pragma unroll
            for (int mt = 0; mt < 4; ++mt)
                #pragma unroll
                for (int nt = 0; nt < 4; ++nt)
                    acc[mt][nt] = __builtin_amdgcn_mfma_f32_16x16x32_bf16(af[mt], bfr[nt], acc[mt][nt], 0, 0, 0);
        }
        __syncthreads();
    }
    // epilogue: p = sum_nt relu(acc + b2[col]) * v[col]; reduce over l15; store
    float vb[4], bb[4];
    #pragma unroll
    for (int nt = 0; nt < 4; ++nt) {
        const int col = n0 + wn*64 + nt*16 + l15;
        bb[nt] = b2[(z+1)*512 + col];
        vb[nt] = vq[z*512 + col];
    }
    const int plane2 = plane * 2 + wn;       // 0..7
    const int gq = lane >> 4;
    #pragma unroll
    for (int mt = 0; mt < 4; ++mt)
        #pragma unroll
        for (int r = 0; r < 4; ++r) {
            float p = 0.f;
            #pragma unroll
            for (int nt = 0; nt < 4; ++nt)
                p = fmaf(fmaxf(acc[mt][nt][r] + bb[nt], 0.f), vb[nt], p);
            p += __shfl_xor(p, 1, 64);
            p += __shfl_xor(p, 2, 64);
            p += __shfl_xor(p, 4, 64);
            p += __shfl_xor(p, 8, 64);
            if (l15 == 0) {
                const int grow = r0 + wm*64 + mt*16 + gq*4 + r;
                qpart[(size_t)plane2 * 76800 + grow] = p;
            }
        }
}

// ---------------- lse: out[b] = logsumexp([q[b,0:600], zeros(100)]) ----------
__global__ void lse_kernel(const float* __restrict__ qpart, const float* __restrict__ QOFF,
                           float* __restrict__ out) {
    __shared__ float red[256];
    __shared__ float qs[QW];
    const int b = blockIdx.x, t = threadIdx.x;
    for (int k = t; k < QW; k += 256) {
        const int z = k / 100, gc = k - z * 100;
        const int grow = z * 12800 + b * 100 + gc;
        float s = QOFF[z * 128 + b];
        #pragma unroll
        for (int p = 0; p < 8; ++p) s += qpart[(size_t)p * 76800 + grow];
        qs[k] = s;
    }
    __syncthreads();
    float m = 0.0f;   // zero tail participates in the max
    for (int k = t; k < QW; k += 256) m = fmaxf(m, qs[k]);
    red[t] = m; __syncthreads();
    for (int s = 128; s > 0; s >>= 1) { if (t < s) red[t] = fmaxf(red[t], red[t+s]); __syncthreads(); }
    m = red[0]; __syncthreads();
    float sum = 0.0f;
    for (int k = t; k < QW; k += 256) sum += expf(qs[k] - m);
    red[t] = sum; __syncthreads();
    for (int s = 128; s > 0; s >>= 1) { if (t < s) red[t] += red[t+s]; __syncthreads(); }
    if (t == 0) out[b] = logf(red[0] + 100.0f * expf(-m)) + m;
}

extern "C" void kernel_launch(void* const* d_in, const int* in_sizes, int n_in,
                              void* d_out, int out_size, void* d_ws, size_t ws_size,
                              hipStream_t stream) {
    const float* obs     = (const float*)d_in[0];
    const float* actions = (const float*)d_in[1];
    const float* W1      = (const float*)d_in[2];
    const float* b1      = (const float*)d_in[3];
    const float* W2      = (const float*)d_in[4];
    const float* b2      = (const float*)d_in[5];
    const float* W3      = (const float*)d_in[6];
    const float* b3      = (const float*)d_in[7];
    const float* Wp      = (const float*)d_in[8];
    const float* bp      = (const float*)d_in[9];
    float* out = (float*)d_out;
    float* ws  = (float*)d_ws;

    // workspace layout (float offsets)
    unsigned short* obs_bf = (unsigned short*)(ws);            // 32768 f
    unsigned short* W1AT   = (unsigned short*)(ws + 32768);    // 786432 f
    unsigned short* W2T    = (unsigned short*)(ws + 819200);   // 786432 f
    unsigned short* W1Cbf  = (unsigned short*)(ws + 1605632);  // 196608 f
    unsigned short* W2bf   = (unsigned short*)(ws + 1802240);  // 786432 f
    unsigned short* W3bf   = (unsigned short*)(ws + 2588672);  // 196608 f
    float* Yobs  = ws + 2785280;                               // 393216 f
    float* Y0all = ws + 3178496;                               // 393216 f
    float* QOFF  = ws + 3571712;                               // 1024 f
    float* vq    = ws + 3572736;                               // 3072 f
    float* qpart = ws + 3575808;                               // 614400 f
    unsigned short* H1 = (unsigned short*)(ws + 4190208);      // 19660800 f

    prep_kernel<<<5452, 256, 0, stream>>>(obs, W1, W2, W3, Wp,
                                          obs_bf, W1Cbf, W2bf, W3bf, W1AT, W2T, vq);
    yobs_kernel<<<dim3(2,4,6), 256, 0, stream>>>(obs_bf, W1AT, b1, Yobs);
    chain_kernel<<<BATCH, 1024, 0, stream>>>(Yobs, W1, W1Cbf, W2bf, W3bf, b2, b3, actions, Wp, bp, Y0all, QOFF);
    h1all_kernel<<<19200, 256, 0, stream>>>(Y0all, W1, H1);
    gemm2q_kernel<<<2400, 256, 0, stream>>>(H1, W2T, b2, vq, qpart);
    lse_kernel<<<BATCH, 256, 0, stream>>>(qpart, QOFF, out);
}